// Round 1
// baseline (9769.023 us; speedup 1.0000x reference)
//
#include <hip/hip_runtime.h>
#include <stdint.h>

// GPT-2 small forward: B=2,S=1024,D=768,H=12,L=12,V=50257
#define V_SZ 50257
#define D_SZ 768
#define H_SZ 12
#define L_SZ 12
#define FF_SZ 3072
#define BS 2
#define SEQ 1024
#define M_TOK 2048  // B*S

typedef __attribute__((ext_vector_type(8))) short short8;
typedef __attribute__((ext_vector_type(4))) float f32x4;

__device__ __forceinline__ float b2f(unsigned short u) {
  union { unsigned int i; float f; } c; c.i = ((unsigned int)u) << 16; return c.f;
}
__device__ __forceinline__ unsigned short f2b(float f) {
  unsigned int x = __float_as_uint(f);
  unsigned int r = (x + 0x7fffu + ((x >> 16) & 1u)) >> 16;  // RNE
  return (unsigned short)r;
}

// ---------------- weight transpose+convert: src fp32 [K,N] -> dst bf16 [N,K], batched over z
__global__ __launch_bounds__(256)
void transpose_conv(const float* __restrict__ src, unsigned short* __restrict__ dst,
                    int K, int N)
{
  __shared__ float t[64][65];
  int k0 = blockIdx.y * 64, n0 = blockIdx.x * 64;
  size_t base = (size_t)blockIdx.z * K * N;
  src += base; dst += base;
  int tid = threadIdx.x;
#pragma unroll
  for (int i = 0; i < 4; ++i) {
    int lin = tid + i * 256;
    int rr = lin >> 4;
    int c4 = (lin & 15) << 2;
    float4 v = *(const float4*)(src + (size_t)(k0 + rr) * N + n0 + c4);
    t[rr][c4 + 0] = v.x; t[rr][c4 + 1] = v.y; t[rr][c4 + 2] = v.z; t[rr][c4 + 3] = v.w;
  }
  __syncthreads();
#pragma unroll
  for (int i = 0; i < 4; ++i) {
    int lin = tid + i * 256;
    int nr = lin >> 4;
    int kc = (lin & 15) << 2;
    ushort4 o;
    o.x = f2b(t[kc + 0][nr]); o.y = f2b(t[kc + 1][nr]);
    o.z = f2b(t[kc + 2][nr]); o.w = f2b(t[kc + 3][nr]);
    *(ushort4*)(dst + (size_t)(n0 + nr) * K + k0 + kc) = o;
  }
}

// ---------------- fp32 -> bf16 convert (wte, already [N,K])
__global__ void conv_bf16(const float* __restrict__ src, unsigned short* __restrict__ dst, int n4)
{
  int i = blockIdx.x * 256 + threadIdx.x;
  if (i >= n4) return;
  float4 v = ((const float4*)src)[i];
  ushort4 o;
  o.x = f2b(v.x); o.y = f2b(v.y); o.z = f2b(v.z); o.w = f2b(v.w);
  ((ushort4*)dst)[i] = o;
}

// ---------------- embedding: x = wte[tok] + wpe[s]  (fp32)
__global__ void embed_kernel(const int* __restrict__ tok, const float* __restrict__ wte,
                             const float* __restrict__ wpe, float* __restrict__ x)
{
  int row = blockIdx.x, tid = threadIdx.x;
  int t = tok[row];
  int s = row & (SEQ - 1);
#pragma unroll
  for (int i = 0; i < 3; ++i) {
    int d = tid + i * 256;
    x[(size_t)row * D_SZ + d] = wte[(size_t)t * D_SZ + d] + wpe[(size_t)s * D_SZ + d];
  }
}

// ---------------- LayerNorm (fp32 in) -> bf16 out
__global__ __launch_bounds__(256)
void ln_kernel(const float* __restrict__ x, const float* __restrict__ g,
               const float* __restrict__ b, unsigned short* __restrict__ out)
{
  __shared__ float red[256];
  int row = blockIdx.x, tid = threadIdx.x;
  const float* xr = x + (size_t)row * D_SZ;
  float v0 = xr[tid], v1 = xr[tid + 256], v2 = xr[tid + 512];
  red[tid] = v0 + v1 + v2; __syncthreads();
  for (int st = 128; st > 0; st >>= 1) { if (tid < st) red[tid] += red[tid + st]; __syncthreads(); }
  float mean = red[0] * (1.f / 768.f); __syncthreads();
  float d0 = v0 - mean, d1 = v1 - mean, d2 = v2 - mean;
  red[tid] = d0 * d0 + d1 * d1 + d2 * d2; __syncthreads();
  for (int st = 128; st > 0; st >>= 1) { if (tid < st) red[tid] += red[tid + st]; __syncthreads(); }
  float rstd = rsqrtf(red[0] * (1.f / 768.f) + 1e-5f);
  unsigned short* o = out + (size_t)row * D_SZ;
  o[tid]       = f2b(d0 * rstd * g[tid]       + b[tid]);
  o[tid + 256] = f2b(d1 * rstd * g[tid + 256] + b[tid + 256]);
  o[tid + 512] = f2b(d2 * rstd * g[tid + 512] + b[tid + 512]);
}

// ---------------- GEMM: C[M,N] = A[M,K](bf16) * Bt[N,K]^T(bf16)
// EPI 0: +bias -> bf16 Cb     EPI 1: +bias, GELU -> bf16 Cb
// EPI 2: +bias, += residual (Cf fp32 in/out)   EPI 3: head, fp32 store, col<N guard
#define BM 128
#define BN 128
#define BK 64

__device__ __forceinline__ void gload16(const void* g, void* l) {
  __builtin_amdgcn_global_load_lds((const __attribute__((address_space(1))) void*)g,
                                   (__attribute__((address_space(3))) void*)l, 16, 0, 0);
}

template <int EPI>
__global__ __launch_bounds__(256)
void gemm_nt(const unsigned short* __restrict__ A, const unsigned short* __restrict__ Bt,
             const float* __restrict__ bias, unsigned short* __restrict__ Cb,
             float* __restrict__ Cf, int M, int N, int K, int ldc)
{
  __shared__ __attribute__((aligned(1024))) unsigned short ldsA[BM * BK];
  __shared__ __attribute__((aligned(1024))) unsigned short ldsB[BN * BK];
  const int tid = threadIdx.x;
  const int lane = tid & 63;
  const int wv = tid >> 6;
  const int wr = wv >> 1, wc = wv & 1;
  const int m0 = blockIdx.y * BM, n0 = blockIdx.x * BN;

  f32x4 acc[4][4];
#pragma unroll
  for (int i = 0; i < 4; ++i)
#pragma unroll
    for (int j = 0; j < 4; ++j) acc[i][j] = (f32x4){0.f, 0.f, 0.f, 0.f};

  char* lA = (char*)ldsA;
  char* lB = (char*)ldsB;

  for (int kt = 0; kt < K; kt += BK) {
    // stage A,B tiles: st_16x32-swizzled content via pre-swizzled global source (m173/m201)
#pragma unroll
    for (int i = 0; i < 4; ++i) {
      int off = i * 4096 + tid * 16;              // linear byte slot in tile
      int lin = off ^ (((off >> 9) & 1) << 5);    // involution: element that lives here
      int r = lin >> 7;                           // tile row
      int ce = (lin & 127) >> 1;                  // element col (bf16)
      int ldso = i * 4096 + wv * 1024;            // wave-uniform LDS base
      gload16(A + (size_t)(m0 + r) * K + kt + ce, lA + ldso);
      int rb = n0 + r; if (rb > N - 1) rb = N - 1;  // clamp (head tail)
      gload16(Bt + (size_t)rb * K + kt + ce, lB + ldso);
    }
    __syncthreads();
#pragma unroll
    for (int ks = 0; ks < 2; ++ks) {
      short8 av[4], bv[4];
#pragma unroll
      for (int f = 0; f < 4; ++f) {
        int ra = wr * 64 + f * 16 + (lane & 15);
        int aa = ra * 128 + ((ks * 64 + ((lane >> 4) << 4)) ^ ((ra & 4) << 3));
        av[f] = *(const short8*)(lA + aa);
        int rb2 = wc * 64 + f * 16 + (lane & 15);
        int ab = rb2 * 128 + ((ks * 64 + ((lane >> 4) << 4)) ^ ((rb2 & 4) << 3));
        bv[f] = *(const short8*)(lB + ab);
      }
#pragma unroll
      for (int fm = 0; fm < 4; ++fm)
#pragma unroll
        for (int fn = 0; fn < 4; ++fn)
          acc[fm][fn] = __builtin_amdgcn_mfma_f32_16x16x32_bf16(av[fm], bv[fn], acc[fm][fn], 0, 0, 0);
    }
    __syncthreads();
  }

  // epilogue: C/D map col=lane&15, row=(lane>>4)*4+j  (m89/m91)
  const int colb = n0 + wc * 64;
  const int rowb = m0 + wr * 64;
#pragma unroll
  for (int fm = 0; fm < 4; ++fm) {
#pragma unroll
    for (int fn = 0; fn < 4; ++fn) {
      int col = colb + fn * 16 + (lane & 15);
      int r0 = rowb + fm * 16 + ((lane >> 4) << 2);
      f32x4 v = acc[fm][fn];
      float bs = (EPI == 3) ? 0.f : bias[col];
#pragma unroll
      for (int j = 0; j < 4; ++j) {
        int row = r0 + j;
        float val = v[j] + bs;
        if (EPI == 0) {
          Cb[(size_t)row * ldc + col] = f2b(val);
        } else if (EPI == 1) {
          float ge = 0.5f * val * (1.f + erff(val * 0.7071067811865475f));
          Cb[(size_t)row * ldc + col] = f2b(ge);
        } else if (EPI == 2) {
          float* p = Cf + (size_t)row * ldc + col;
          *p = *p + val;
        } else {
          if (col < N) Cf[(size_t)row * ldc + col] = v[j];
        }
      }
    }
  }
}

// ---------------- attention: one block per (b,h,q). qkv bf16 [M,3D]; out bf16 [M,D]
__global__ __launch_bounds__(256)
void attn_kernel(const unsigned short* __restrict__ qkv, unsigned short* __restrict__ out)
{
  __shared__ float sc[SEQ];
  __shared__ float qv[64];
  __shared__ float red[256];
  const int tid = threadIdx.x;
  int bid = blockIdx.x;
  int q = bid & (SEQ - 1);
  int h = (bid >> 10) % H_SZ;
  int b = bid / (H_SZ * SEQ);
  const size_t rowq = (size_t)(b * SEQ + q) * (3 * D_SZ);
  if (tid < 64) qv[tid] = b2f(qkv[rowq + h * 64 + tid]);
  __syncthreads();
  const float scale = 0.03608439182435161f;  // 1/sqrt(768) — embed-dim quirk
  for (int kp = tid; kp <= q; kp += 256) {
    const unsigned short* kr = qkv + (size_t)(b * SEQ + kp) * (3 * D_SZ) + D_SZ + h * 64;
    const ushort4* k4 = (const ushort4*)kr;
    float dot = 0.f;
#pragma unroll
    for (int i = 0; i < 16; ++i) {
      ushort4 u = k4[i];
      dot += qv[4 * i + 0] * b2f(u.x) + qv[4 * i + 1] * b2f(u.y)
           + qv[4 * i + 2] * b2f(u.z) + qv[4 * i + 3] * b2f(u.w);
    }
    sc[kp] = dot * scale;
  }
  __syncthreads();
  float m = -3.4e38f;
  for (int kp = tid; kp <= q; kp += 256) m = fmaxf(m, sc[kp]);
  red[tid] = m; __syncthreads();
  for (int st = 128; st > 0; st >>= 1) { if (tid < st) red[tid] = fmaxf(red[tid], red[tid + st]); __syncthreads(); }
  m = red[0]; __syncthreads();
  float sum = 0.f;
  for (int kp = tid; kp <= q; kp += 256) { float e = __expf(sc[kp] - m); sc[kp] = e; sum += e; }
  red[tid] = sum; __syncthreads();
  for (int st = 128; st > 0; st >>= 1) { if (tid < st) red[tid] += red[tid + st]; __syncthreads(); }
  float inv = 1.f / red[0];
  __syncthreads();
  int d = tid & 63, gq = tid >> 6;
  float acc = 0.f;
  for (int kp = gq; kp <= q; kp += 4)
    acc += sc[kp] * b2f(qkv[(size_t)(b * SEQ + kp) * (3 * D_SZ) + 2 * D_SZ + h * 64 + d]);
  red[gq * 64 + d] = acc;
  __syncthreads();
  if (gq == 0) {
    float o = (red[d] + red[64 + d] + red[128 + d] + red[192 + d]) * inv;
    out[(size_t)(b * SEQ + q) * D_SZ + h * 64 + d] = f2b(o);
  }
}

// ---------------- in-place log_softmax on logits + CE loss (double-LSM collapses: lp2==lp1)
__global__ __launch_bounds__(256)
void lsm_loss_kernel(float* __restrict__ logits, const int* __restrict__ target,
                     float* __restrict__ loss)
{
  __shared__ float ms[256], ss[256];
  int row = blockIdx.x, tid = threadIdx.x;
  float* xr = logits + (size_t)row * V_SZ;
  float m = -3.4e38f, s = 0.f;
  for (int j = tid; j < V_SZ; j += 256) {
    float x = xr[j];
    float m2 = fmaxf(m, x);
    s = s * __expf(m - m2) + __expf(x - m2);
    m = m2;
  }
  ms[tid] = m; ss[tid] = s; __syncthreads();
  for (int st = 128; st > 0; st >>= 1) {
    if (tid < st) {
      float m1 = ms[tid], m2 = ms[tid + st];
      float mn = fmaxf(m1, m2);
      ss[tid] = ss[tid] * __expf(m1 - mn) + ss[tid + st] * __expf(m2 - mn);
      ms[tid] = mn;
    }
    __syncthreads();
  }
  float lse = ms[0] + logf(ss[0]);
  if (tid == 0) {
    float xt = xr[target[row]];
    atomicAdd(loss, -(xt - lse) * (1.f / 2048.f));
  }
  __syncthreads();
  for (int j = tid; j < V_SZ; j += 256) xr[j] = xr[j] - lse;
}

// ---------------- orchestration
extern "C" void kernel_launch(void* const* d_in, const int* in_sizes, int n_in,
                              void* d_out, int out_size, void* d_ws, size_t ws_size,
                              hipStream_t stream)
{
  const int*   tokens = (const int*)d_in[0];
  const int*   target = (const int*)d_in[1];
  const float* wte    = (const float*)d_in[2];
  const float* wpe    = (const float*)d_in[3];
  const float* ln1_g  = (const float*)d_in[4];
  const float* ln1_b  = (const float*)d_in[5];
  const float* qkv_w  = (const float*)d_in[6];
  const float* qkv_b  = (const float*)d_in[7];
  const float* proj_w = (const float*)d_in[8];
  const float* proj_b = (const float*)d_in[9];
  const float* ln2_g  = (const float*)d_in[10];
  const float* ln2_b  = (const float*)d_in[11];
  const float* fc1_w  = (const float*)d_in[12];
  const float* fc1_b  = (const float*)d_in[13];
  const float* fc2_w  = (const float*)d_in[14];
  const float* fc2_b  = (const float*)d_in[15];
  const float* lnf_g  = (const float*)d_in[16];
  const float* lnf_b  = (const float*)d_in[17];
  float* out = (float*)d_out;

  auto al = [](size_t x) { return (x + 255) & ~(size_t)255; };
  size_t sz_wqkv = al((size_t)L_SZ * D_SZ * 3 * D_SZ * 2);
  size_t sz_wproj = al((size_t)L_SZ * D_SZ * D_SZ * 2);
  size_t sz_wfc1 = al((size_t)L_SZ * D_SZ * FF_SZ * 2);
  size_t sz_wfc2 = al((size_t)L_SZ * FF_SZ * D_SZ * 2);
  size_t need_w = sz_wqkv + sz_wproj + sz_wfc1 + sz_wfc2;  // ~170 MB
  size_t sz_wte = al((size_t)V_SZ * D_SZ * 2);
  size_t sz_x   = al((size_t)M_TOK * D_SZ * 4);
  size_t sz_h   = al((size_t)M_TOK * D_SZ * 2);
  size_t sz_qkv = al((size_t)M_TOK * 3 * D_SZ * 2);
  size_t sz_att = al((size_t)M_TOK * D_SZ * 2);
  size_t sz_ffh = al((size_t)M_TOK * FF_SZ * 2);
  size_t need_r = sz_wte + sz_x + sz_h + sz_qkv + sz_att + sz_ffh;  // ~112 MB

  char* wsc = (char*)d_ws;
  char* wb;
  char* rbp;
  if (ws_size >= need_w + need_r) { wb = wsc; rbp = wsc + need_w; }
  else { wb = (char*)d_out; rbp = wsc; }  // d_out (412MB) as weight scratch; fully rewritten later

  unsigned short* Wqkv  = (unsigned short*)wb; wb += sz_wqkv;
  unsigned short* Wproj = (unsigned short*)wb; wb += sz_wproj;
  unsigned short* Wfc1  = (unsigned short*)wb; wb += sz_wfc1;
  unsigned short* Wfc2  = (unsigned short*)wb; wb += sz_wfc2;
  unsigned short* Wte   = (unsigned short*)rbp; rbp += sz_wte;
  float*          x     = (float*)rbp; rbp += sz_x;
  unsigned short* hbuf  = (unsigned short*)rbp; rbp += sz_h;
  unsigned short* qkvb  = (unsigned short*)rbp; rbp += sz_qkv;
  unsigned short* attb  = (unsigned short*)rbp; rbp += sz_att;
  unsigned short* ffh   = (unsigned short*)rbp; rbp += sz_ffh;

  float* loss = out + (size_t)M_TOK * V_SZ;

  // per-call weight prep (harness re-poisons ws/out every launch)
  transpose_conv<<<dim3(36, 12, 12), 256, 0, stream>>>(qkv_w, Wqkv, D_SZ, 3 * D_SZ);
  transpose_conv<<<dim3(12, 12, 12), 256, 0, stream>>>(proj_w, Wproj, D_SZ, D_SZ);
  transpose_conv<<<dim3(48, 12, 12), 256, 0, stream>>>(fc1_w, Wfc1, D_SZ, FF_SZ);
  transpose_conv<<<dim3(12, 48, 12), 256, 0, stream>>>(fc2_w, Wfc2, FF_SZ, D_SZ);
  int n4 = V_SZ * D_SZ / 4;
  conv_bf16<<<(n4 + 255) / 256, 256, 0, stream>>>(wte, Wte, n4);
  hipMemsetAsync(loss, 0, 4, stream);

  embed_kernel<<<M_TOK, 256, 0, stream>>>(tokens, wte, wpe, x);

  for (int l = 0; l < L_SZ; ++l) {
    ln_kernel<<<M_TOK, 256, 0, stream>>>(x, ln1_g + l * D_SZ, ln1_b + l * D_SZ, hbuf);
    gemm_nt<0><<<dim3(18, 16), 256, 0, stream>>>(hbuf, Wqkv + (size_t)l * D_SZ * 3 * D_SZ,
                                                 qkv_b + l * 3 * D_SZ, qkvb, nullptr,
                                                 M_TOK, 3 * D_SZ, D_SZ, 3 * D_SZ);
    attn_kernel<<<BS * H_SZ * SEQ, 256, 0, stream>>>(qkvb, attb);
    gemm_nt<2><<<dim3(6, 16), 256, 0, stream>>>(attb, Wproj + (size_t)l * D_SZ * D_SZ,
                                                proj_b + l * D_SZ, nullptr, x,
                                                M_TOK, D_SZ, D_SZ, D_SZ);
    ln_kernel<<<M_TOK, 256, 0, stream>>>(x, ln2_g + l * D_SZ, ln2_b + l * D_SZ, hbuf);
    gemm_nt<1><<<dim3(24, 16), 256, 0, stream>>>(hbuf, Wfc1 + (size_t)l * D_SZ * FF_SZ,
                                                 fc1_b + l * FF_SZ, ffh, nullptr,
                                                 M_TOK, FF_SZ, D_SZ, FF_SZ);
    gemm_nt<2><<<dim3(6, 16), 256, 0, stream>>>(ffh, Wfc2 + (size_t)l * FF_SZ * D_SZ,
                                                fc2_b + l * D_SZ, nullptr, x,
                                                M_TOK, D_SZ, FF_SZ, D_SZ);
  }

  ln_kernel<<<M_TOK, 256, 0, stream>>>(x, lnf_g, lnf_b, hbuf);
  gemm_nt<3><<<dim3((V_SZ + 127) / 128, 16), 256, 0, stream>>>(hbuf, Wte, nullptr, nullptr,
                                                               out, M_TOK, V_SZ, D_SZ, V_SZ);
  lsm_loss_kernel<<<M_TOK, 256, 0, stream>>>(out, target, loss);
}